// Round 7
// baseline (574.922 us; speedup 1.0000x reference)
//
#include <hip/hip_runtime.h>

#define NN 1024
#define FIN 512
#define HH1 256
#define HH2 128
#define MTOT 32768   // B*N total rows

typedef unsigned short ushort_t;
using bf16x8 = __attribute__((ext_vector_type(8))) short;
using f32x4  = __attribute__((ext_vector_type(4))) float;

__device__ __forceinline__ float leakyf(float x) { return fmaxf(x, 0.01f * x); }
__device__ __forceinline__ float eluf(float x) { return x > 0.0f ? x : __expf(x) - 1.0f; }
// pack the high halves of two fp32 bit patterns: [u1.hi : u0.hi]
__device__ __forceinline__ unsigned pack_hi(unsigned u0, unsigned u1) {
  return __builtin_amdgcn_perm(u1, u0, 0x07060302u);
}
// trunc-split two fp32 -> bf16 hi pair + bf16 lo pair (lo compensates hi trunc)
__device__ __forceinline__ void split_pack2(float f0, float f1, unsigned& hp, unsigned& lp) {
  unsigned u0 = __float_as_uint(f0), u1 = __float_as_uint(f1);
  hp = pack_hi(u0, u1);
  float l0 = f0 - __uint_as_float(u0 & 0xFFFF0000u);
  float l1 = f1 - __uint_as_float(u1 & 0xFFFF0000u);
  lp = pack_hi(__float_as_uint(l0), __float_as_uint(l1));
}
// RNE-round two fp32 to bf16 and pack
__device__ __forceinline__ unsigned pack_rne(float f0, float f1) {
  unsigned u0 = __float_as_uint(f0); u0 += 0x7FFFu + ((u0 >> 16) & 1u);
  unsigned u1 = __float_as_uint(f1); u1 += 0x7FFFu + ((u1 >> 16) & 1u);
  return pack_hi(u0, u1);
}

// ---------------------------------------------------------------------------
// W[K][N] fp32 -> WT[N][K] trunc-split bf16. K = 1<<kshift.
// ---------------------------------------------------------------------------
__global__ __launch_bounds__(256) void transpose_w_split(const float* __restrict__ W,
                                                         ushort_t* __restrict__ WThi,
                                                         ushort_t* __restrict__ WTlo,
                                                         int Nc, int kshift) {
  int idx = blockIdx.x * 256 + threadIdx.x;
  int k = idx & ((1 << kshift) - 1);
  int n = idx >> kshift;
  float f = W[(size_t)k * Nc + n];
  unsigned u = __float_as_uint(f);
  WThi[idx] = (ushort_t)(u >> 16);
  float lo = f - __uint_as_float(u & 0xFFFF0000u);
  WTlo[idx] = (ushort_t)(__float_as_uint(lo) >> 16);
}

// ---------------------------------------------------------------------------
// Producer GEMM, full split precision (3 MFMA): C = A(fp32)[M,K] @ B, with
// B transposed split BT[NC][K]. Block tile 64 x NCB; gridDim.y = NC/NCB.
// REGISTER-DIRECT K-loop: the 16x16x32 fragment of lane (ln,quad) is a
// contiguous 16-32B chunk of the row-major operands, so A and B fragments
// are loaded straight from global into registers. NO LDS, NO barriers in
// the loop — waves free-run and the compiler pipelines loads across
// iterations (5 rounds of tuning the staged-LDS/barrier loop were neutral;
// this removes the structure entirely).
// Outputs: CT split, tile-blocked CT_t[tile=M/64][NC][64]; el/er partial row
// dots atomicAdd'ed across n-blocks (pre-zeroed).
// ---------------------------------------------------------------------------
template<int NC, int NCB>
__global__ __launch_bounds__(256, 2) void gemm_asplit(const float* __restrict__ A,
                                                      const ushort_t* __restrict__ BThi,
                                                      const ushort_t* __restrict__ BTlo,
                                                      const float* __restrict__ avec,
                                                      ushort_t* __restrict__ CThi,
                                                      ushort_t* __restrict__ CTlo,
                                                      float* __restrict__ el,
                                                      float* __restrict__ er, int K) {
  constexpr int NFR = NCB / 32;   // n-frags per wave (wave tile 32 x NCB/2)
  __shared__ ushort_t stg[NCB * 66];   // CT epilogue staging only
  const int t = threadIdx.x, lane = t & 63, wid = t >> 6;
  const int wm = (wid & 1) * 32, wn = (wid >> 1) * (NCB / 2);
  const int ln = lane & 15, quad = lane >> 4;
  const int m0 = blockIdx.x * 64;
  const int n0c = blockIdx.y * NCB;
  // direct fragment base pointers (lane-contiguous chunks)
  const float*    ap0 = A + (size_t)(m0 + wm + ln) * K + quad * 8;
  const float*    ap1 = ap0 + (size_t)16 * K;
  const ushort_t* bh0 = BThi + (size_t)(n0c + wn + ln) * K + quad * 8;
  const ushort_t* bl0 = BTlo + (size_t)(n0c + wn + ln) * K + quad * 8;
  f32x4 acc[2][NFR];
#pragma unroll
  for (int mi = 0; mi < 2; ++mi)
#pragma unroll
    for (int ni = 0; ni < NFR; ++ni) acc[mi][ni] = (f32x4){0.f, 0.f, 0.f, 0.f};

  for (int k0 = 0; k0 < K; k0 += 32) {
    bf16x8 ahf[2], alf[2];
    {
      float4 f0 = *(const float4*)(ap0 + k0);
      float4 f1 = *(const float4*)(ap0 + k0 + 4);
      uint4 hv, lv;
      split_pack2(f0.x, f0.y, hv.x, lv.x);
      split_pack2(f0.z, f0.w, hv.y, lv.y);
      split_pack2(f1.x, f1.y, hv.z, lv.z);
      split_pack2(f1.z, f1.w, hv.w, lv.w);
      ahf[0] = *(bf16x8*)&hv; alf[0] = *(bf16x8*)&lv;
    }
    {
      float4 f0 = *(const float4*)(ap1 + k0);
      float4 f1 = *(const float4*)(ap1 + k0 + 4);
      uint4 hv, lv;
      split_pack2(f0.x, f0.y, hv.x, lv.x);
      split_pack2(f0.z, f0.w, hv.y, lv.y);
      split_pack2(f1.x, f1.y, hv.z, lv.z);
      split_pack2(f1.z, f1.w, hv.w, lv.w);
      ahf[1] = *(bf16x8*)&hv; alf[1] = *(bf16x8*)&lv;
    }
    bf16x8 bhf[NFR], blf[NFR];
#pragma unroll
    for (int i = 0; i < NFR; ++i) {
      uint4 vh = *(const uint4*)(bh0 + (size_t)i * 16 * K + k0);
      uint4 vl = *(const uint4*)(bl0 + (size_t)i * 16 * K + k0);
      bhf[i] = *(bf16x8*)&vh; blf[i] = *(bf16x8*)&vl;
    }
#pragma unroll
    for (int mi = 0; mi < 2; ++mi)
#pragma unroll
      for (int ni = 0; ni < NFR; ++ni) {
        acc[mi][ni] = __builtin_amdgcn_mfma_f32_16x16x32_bf16(ahf[mi], bhf[ni], acc[mi][ni], 0, 0, 0);
        acc[mi][ni] = __builtin_amdgcn_mfma_f32_16x16x32_bf16(ahf[mi], blf[ni], acc[mi][ni], 0, 0, 0);
        acc[mi][ni] = __builtin_amdgcn_mfma_f32_16x16x32_bf16(alf[mi], bhf[ni], acc[mi][ni], 0, 0, 0);
      }
  }

  // ---- el/er partial row-dot reduction over this block's NCB cols ----
  float aLc[NFR], aRc[NFR];
#pragma unroll
  for (int ni = 0; ni < NFR; ++ni) {
    aLc[ni] = avec[n0c + wn + ni * 16 + ln];
    aRc[ni] = avec[NC + n0c + wn + ni * 16 + ln];
  }
#pragma unroll
  for (int mi = 0; mi < 2; ++mi) {
    const int mr = m0 + wm + mi * 16 + quad * 4;
#pragma unroll
    for (int rr = 0; rr < 4; ++rr) {
      float vel = 0.f, ver = 0.f;
#pragma unroll
      for (int ni = 0; ni < NFR; ++ni) {
        vel = fmaf(acc[mi][ni][rr], aLc[ni], vel);
        ver = fmaf(acc[mi][ni][rr], aRc[ni], ver);
      }
#pragma unroll
      for (int m = 1; m < 16; m <<= 1) {
        vel += __shfl_xor(vel, m);
        ver += __shfl_xor(ver, m);
      }
      if (ln == 0) {
        atomicAdd(&el[mr + rr], vel);
        atomicAdd(&er[mr + rr], ver);
      }
    }
  }

  // ---- staged CT write, tile-blocked: contiguous [NCB][64] slice ----
  ushort_t* dsthi = CThi + (size_t)blockIdx.x * (NC * 64) + (size_t)n0c * 64;
  ushort_t* dstlo = CTlo + (size_t)blockIdx.x * (NC * 64) + (size_t)n0c * 64;
  const int colbase = wid * (NCB / 4);
  const int g = lane >> 2, j = lane & 3;
#pragma unroll
  for (int pass = 0; pass < 2; ++pass) {
    if (pass) __syncthreads();   // protect pass-0 reads from pass-1 writes
#pragma unroll
    for (int mi = 0; mi < 2; ++mi) {
      const int rbase = wm + mi * 16 + quad * 4;
#pragma unroll
      for (int ni = 0; ni < NFR; ++ni) {
        const int c = wn + ni * 16 + ln;
        unsigned h01, l01, h23, l23;
        split_pack2(acc[mi][ni][0], acc[mi][ni][1], h01, l01);
        split_pack2(acc[mi][ni][2], acc[mi][ni][3], h23, l23);
        uint2 v = pass ? make_uint2(l01, l23) : make_uint2(h01, h23);
        *(uint2*)&stg[c * 66 + rbase] = v;
      }
    }
    __syncthreads();
    ushort_t* dst = pass ? dstlo : dsthi;
#pragma unroll
    for (int cc = 0; cc < NCB / 64; ++cc) {
      const int col = colbase + cc * 16 + g;
#pragma unroll
      for (int half = 0; half < 2; ++half) {
        const int r = half * 32 + j * 8;
        *(uint4*)&dst[col * 64 + r] = *(const uint4*)&stg[col * 66 + r];
      }
    }
  }
}

// Per-batch min/max of el, er -> (mn, 30/(mx-mn)); leaky is monotone.
__global__ __launch_bounds__(256) void minmax_params(const float* __restrict__ el,
                                                     const float* __restrict__ er,
                                                     float2* __restrict__ params) {
  __shared__ float smnl[256], smxl[256], smnr[256], smxr[256];
  const int b = blockIdx.x, t = threadIdx.x;
  float mnl = 3.4e38f, mxl = -3.4e38f, mnr = 3.4e38f, mxr = -3.4e38f;
  for (int i = t; i < NN; i += 256) {
    float v = el[b * NN + i];
    mnl = fminf(mnl, v); mxl = fmaxf(mxl, v);
    float u = er[b * NN + i];
    mnr = fminf(mnr, u); mxr = fmaxf(mxr, u);
  }
  smnl[t] = mnl; smxl[t] = mxl; smnr[t] = mnr; smxr[t] = mxr;
  __syncthreads();
  for (int s = 128; s > 0; s >>= 1) {
    if (t < s) {
      smnl[t] = fminf(smnl[t], smnl[t + s]);
      smxl[t] = fmaxf(smxl[t], smxl[t + s]);
      smnr[t] = fminf(smnr[t], smnr[t + s]);
      smxr[t] = fmaxf(smxr[t], smxr[t + s]);
    }
    __syncthreads();
  }
  if (t == 0) {
    float mn = leakyf(smnl[0] + smnr[0]);
    float mx = leakyf(smxl[0] + smxr[0]);
    params[b] = make_float2(mn, 30.0f / (mx - mn));
  }
}

// ---------------------------------------------------------------------------
// Attention MFMA GEMM: C[i,f] = sum_j att(i,j)*h[j,f]. att synthesized fp32,
// RNE bf16 hi-only A-operand; h split B-operand (2 MFMA). Block 64 x BW,
// gridDim.y = Nc/BW. h is in TILE-BLOCKED layout CT_t[tile][Nc][64].
// REGISTER-DIRECT K-loop: each lane COMPUTES its att fragment directly
// (16 sigmoids/lane, duplicated across wave-pairs) and loads its h fragment
// straight from global. Only LDS use is the read-only ers[] table
// (broadcast reads, no barriers in the loop).
// doElu: stage-1 epilogue. wg!=null: fuse wv[row] += sum_{f in block} C*wg[f].
// ---------------------------------------------------------------------------
template<int BW>
__global__ __launch_bounds__(256, 2) void gemm_att2(const float* __restrict__ el,
                                                    const float* __restrict__ er,
                                                    const float2* __restrict__ params,
                                                    const ushort_t* __restrict__ hThi,
                                                    const ushort_t* __restrict__ hTlo,
                                                    float* __restrict__ C,
                                                    const float* __restrict__ wg,
                                                    float* __restrict__ wv,
                                                    int Nc, int doElu) {
  constexpr int NFR = BW / 32;
  __shared__ float ers[NN];
  const int b = blockIdx.z, t = threadIdx.x, lane = t & 63, wid = t >> 6;
  const int wm = (wid & 1) * 32, wn = (wid >> 1) * (BW / 2);
  const int ln = lane & 15, quad = lane >> 4;
  const int m0 = blockIdx.x * 64, n0 = blockIdx.y * BW;
  const float2 p = params[b];
  const float npinv = -p.y;                  // q = exp(-e_s)
  const float npc   = p.x * p.y + 20.0f;
  *(float4*)&ers[t * 4] = *(const float4*)&er[b * NN + t * 4];
  const float elv0 = el[b * NN + m0 + wm + ln];
  const float elv1 = el[b * NN + m0 + wm + 16 + ln];
  const size_t tstride = (size_t)Nc * 64;                 // ushorts per tile
  const ushort_t* bh0 = hThi + (size_t)(b * 16) * tstride + (size_t)(n0 + wn + ln) * 64 + quad * 8;
  const ushort_t* bl0 = hTlo + (size_t)(b * 16) * tstride + (size_t)(n0 + wn + ln) * 64 + quad * 8;
  f32x4 acc[2][NFR];
#pragma unroll
  for (int mi = 0; mi < 2; ++mi)
#pragma unroll
    for (int ni = 0; ni < NFR; ++ni) acc[mi][ni] = (f32x4){0.f, 0.f, 0.f, 0.f};
  __syncthreads();   // ers visible

  for (int k0 = 0; k0 < NN; k0 += 32) {
    float e8[8];
    *(float4*)&e8[0] = *(const float4*)&ers[k0 + quad * 8];
    *(float4*)&e8[4] = *(const float4*)&ers[k0 + quad * 8 + 4];
    bf16x8 af[2];
#pragma unroll
    for (int mi = 0; mi < 2; ++mi) {
      const float elv = mi ? elv1 : elv0;
      float s[8];
#pragma unroll
      for (int j = 0; j < 8; ++j) {
        float x = elv + e8[j];
        x = fmaxf(x, 0.01f * x);
        s[j] = __builtin_amdgcn_rcpf(1.0f + __expf(fmaf(x, npinv, npc)));
      }
      uint4 av;
      av.x = pack_rne(s[0], s[1]); av.y = pack_rne(s[2], s[3]);
      av.z = pack_rne(s[4], s[5]); av.w = pack_rne(s[6], s[7]);
      af[mi] = *(bf16x8*)&av;
    }
    const size_t ko = (size_t)(k0 >> 6) * tstride + (size_t)(k0 & 32);
    bf16x8 bhf[NFR], blf[NFR];
#pragma unroll
    for (int i = 0; i < NFR; ++i) {
      uint4 vh = *(const uint4*)(bh0 + ko + i * (16 * 64));
      uint4 vl = *(const uint4*)(bl0 + ko + i * (16 * 64));
      bhf[i] = *(bf16x8*)&vh; blf[i] = *(bf16x8*)&vl;
    }
#pragma unroll
    for (int mi = 0; mi < 2; ++mi)
#pragma unroll
      for (int ni = 0; ni < NFR; ++ni) {
        acc[mi][ni] = __builtin_amdgcn_mfma_f32_16x16x32_bf16(af[mi], bhf[ni], acc[mi][ni], 0, 0, 0);
        acc[mi][ni] = __builtin_amdgcn_mfma_f32_16x16x32_bf16(af[mi], blf[ni], acc[mi][ni], 0, 0, 0);
      }
  }
  float wgl[NFR];
  if (wg) {
#pragma unroll
    for (int ni = 0; ni < NFR; ++ni) wgl[ni] = wg[n0 + wn + ni * 16 + ln];
  }
#pragma unroll
  for (int mi = 0; mi < 2; ++mi) {
    const int mrl = m0 + wm + mi * 16 + quad * 4;         // row within batch
    const size_t mrow = (size_t)b * NN + mrl;
#pragma unroll
    for (int ni = 0; ni < NFR; ++ni) {
      const int c = n0 + wn + ni * 16 + ln;
#pragma unroll
      for (int rr = 0; rr < 4; ++rr) {
        float v = acc[mi][ni][rr];
        if (doElu) v = eluf(v);
        C[(mrow + rr) * Nc + c] = v;
      }
    }
    if (wg) {
#pragma unroll
      for (int rr = 0; rr < 4; ++rr) {
        float vw = 0.f;
#pragma unroll
        for (int ni = 0; ni < NFR; ++ni)
          vw = fmaf(acc[mi][ni][rr], wgl[ni], vw);
#pragma unroll
        for (int m = 1; m < 16; m <<= 1) vw += __shfl_xor(vw, m);
        if (ln == 0) atomicAdd(&wv[b * NN + mrl + rr], vw);
      }
    }
  }
}

// ---------------------------------------------------------------------------
// Fused: fc2[b,i,j] = att2(i,j) (fp32) AND out[b,i] = leaky(sum_j att*w + bg).
// One wave per row i; lanes cover 4 consecutive j each (coalesced float4).
// ---------------------------------------------------------------------------
__global__ __launch_bounds__(256) void final_out_fc2(const float* __restrict__ el,
                                                     const float* __restrict__ er,
                                                     const float2* __restrict__ params,
                                                     const float* __restrict__ w,
                                                     const float* __restrict__ bg,
                                                     float* __restrict__ fc2,
                                                     float* __restrict__ out) {
  const int row  = (blockIdx.x * 256 + threadIdx.x) >> 6;  // b*N+i
  const int lane = threadIdx.x & 63;
  const int b = row >> 10;
  const float2 p = params[b];
  const float npinv = -p.y;
  const float npc   = p.x * p.y + 20.0f;
  const float eli = el[row];
  const float* erb = er + (b << 10);
  const float* wb  = w + (b << 10);
  float* fcrow = fc2 + (size_t)row * NN;
  float s = 0.f;
  for (int j = lane * 4; j < NN; j += 256) {
    float4 e4 = *(const float4*)&erb[j];
    float4 w4 = *(const float4*)&wb[j];
    float4 a;
    a.x = __builtin_amdgcn_rcpf(1.0f + __expf(fmaf(leakyf(eli + e4.x), npinv, npc)));
    a.y = __builtin_amdgcn_rcpf(1.0f + __expf(fmaf(leakyf(eli + e4.y), npinv, npc)));
    a.z = __builtin_amdgcn_rcpf(1.0f + __expf(fmaf(leakyf(eli + e4.z), npinv, npc)));
    a.w = __builtin_amdgcn_rcpf(1.0f + __expf(fmaf(leakyf(eli + e4.w), npinv, npc)));
    s += w4.x * a.x + w4.y * a.y + w4.z * a.z + w4.w * a.w;
    *(float4*)&fcrow[j] = a;
  }
#pragma unroll
  for (int off = 32; off > 0; off >>= 1) s += __shfl_down(s, off);
  if (lane == 0) out[row] = leakyf(s + bg[0]);
}

extern "C" void kernel_launch(void* const* d_in, const int* in_sizes, int n_in,
                              void* d_out, int out_size, void* d_ws, size_t ws_size,
                              hipStream_t stream) {
  (void)in_sizes; (void)n_in; (void)out_size; (void)ws_size;
  const float* x  = (const float*)d_in[0];
  const float* W1 = (const float*)d_in[2];
  const float* a1 = (const float*)d_in[3];
  const float* W2 = (const float*)d_in[4];
  const float* a2 = (const float*)d_in[5];
  const float* Wg = (const float*)d_in[6];
  const float* bg = (const float*)d_in[7];

  float* out = (float*)d_out;               // [B,N,1]   32768
  float* fc2 = out + 32768;                 // [B,N,N]   33554432
  float* g2  = fc2 + 33554432;              // [B,N,H2]  4194304

  // Scratch inside the fc2 region (fc2 is written LAST, by final_out_fc2).
  ushort_t* h1Thi = (ushort_t*)fc2;                     // [512][256][64] tiled
  ushort_t* h1Tlo = (ushort_t*)(fc2 + 4194304);
  float*    g1    = fc2 + 8388608;                      // [32768][256] fp32
  ushort_t* h2Thi = (ushort_t*)(fc2 + 16777216);        // [512][128][64] tiled
  ushort_t* h2Tlo = (ushort_t*)(fc2 + 18874368);

  float* wsf = (float*)d_ws;
  float* el1 = wsf;                          // 32768 each; el1,er1,el2,er2,wv
  float* er1 = wsf + 32768;                  //   contiguous -> single memset
  float* el2 = wsf + 65536;
  float* er2 = wsf + 98304;
  float* wv  = wsf + 131072;
  float2* p1 = (float2*)(wsf + 163840);      // 32 float2
  float2* p2 = (float2*)(wsf + 163904);
  ushort_t* W1Thi = (ushort_t*)(wsf + 163968);   // [256][512]
  ushort_t* W1Tlo = (ushort_t*)(wsf + 229504);
  ushort_t* W2Thi = (ushort_t*)(wsf + 295040);   // [128][256]
  ushort_t* W2Tlo = (ushort_t*)(wsf + 311424);

  dim3 blk(256);
  hipMemsetAsync(wsf, 0, 5u * 32768u * sizeof(float), stream);   // el/er/wv = 0
  transpose_w_split<<<512, blk, 0, stream>>>(W1, W1Thi, W1Tlo, HH1, 9);
  transpose_w_split<<<128, blk, 0, stream>>>(W2, W2Thi, W2Tlo, HH2, 8);
  // Stage 1
  gemm_asplit<HH1, 128><<<dim3(512, 2), blk, 0, stream>>>(x, W1Thi, W1Tlo, a1,
                                                          h1Thi, h1Tlo, el1, er1, FIN);
  minmax_params<<<32, blk, 0, stream>>>(el1, er1, p1);
  gemm_att2<128><<<dim3(16, 2, 32), blk, 0, stream>>>(el1, er1, p1, h1Thi, h1Tlo,
                                                      g1, nullptr, nullptr, HH1, 1);
  // Stage 2
  gemm_asplit<HH2, 64><<<dim3(512, 2), blk, 0, stream>>>(g1, W2Thi, W2Tlo, a2,
                                                         h2Thi, h2Tlo, el2, er2, HH1);
  minmax_params<<<32, blk, 0, stream>>>(el2, er2, p2);
  gemm_att2<64><<<dim3(16, 2, 32), blk, 0, stream>>>(el2, er2, p2, h2Thi, h2Tlo,
                                                     g2, Wg, wv, HH2, 0);
  // Stage 3: fc2 + out (att recomputed on the fly; wv = g2 @ Wg already fused)
  final_out_fc2<<<8192, blk, 0, stream>>>(el2, er2, p2, wv, bg, fc2, out);
}

// Round 9
// 516.788 us; speedup vs baseline: 1.1125x; 1.1125x over previous
//
#include <hip/hip_runtime.h>

#define NN 1024
#define FIN 512
#define HH1 256
#define HH2 128
#define MTOT 32768   // B*N total rows

typedef unsigned short ushort_t;
using bf16x8 = __attribute__((ext_vector_type(8))) short;
using f32x4  = __attribute__((ext_vector_type(4))) float;

__device__ __forceinline__ float leakyf(float x) { return fmaxf(x, 0.01f * x); }
__device__ __forceinline__ float eluf(float x) { return x > 0.0f ? x : __expf(x) - 1.0f; }
// pack the high halves of two fp32 bit patterns: [u1.hi : u0.hi]
__device__ __forceinline__ unsigned pack_hi(unsigned u0, unsigned u1) {
  return __builtin_amdgcn_perm(u1, u0, 0x07060302u);
}
// trunc-split two fp32 -> bf16 hi pair + bf16 lo pair (lo compensates hi trunc)
__device__ __forceinline__ void split_pack2(float f0, float f1, unsigned& hp, unsigned& lp) {
  unsigned u0 = __float_as_uint(f0), u1 = __float_as_uint(f1);
  hp = pack_hi(u0, u1);
  float l0 = f0 - __uint_as_float(u0 & 0xFFFF0000u);
  float l1 = f1 - __uint_as_float(u1 & 0xFFFF0000u);
  lp = pack_hi(__float_as_uint(l0), __float_as_uint(l1));
}
// RNE-round two fp32 to bf16 and pack
__device__ __forceinline__ unsigned pack_rne(float f0, float f1) {
  unsigned u0 = __float_as_uint(f0); u0 += 0x7FFFu + ((u0 >> 16) & 1u);
  unsigned u1 = __float_as_uint(f1); u1 += 0x7FFFu + ((u1 >> 16) & 1u);
  return pack_hi(u0, u1);
}

// ---------------------------------------------------------------------------
// W[K][N] fp32 -> WT[N][K] trunc-split bf16. K = 1<<kshift.
// ---------------------------------------------------------------------------
__global__ __launch_bounds__(256) void transpose_w_split(const float* __restrict__ W,
                                                         ushort_t* __restrict__ WThi,
                                                         ushort_t* __restrict__ WTlo,
                                                         int Nc, int kshift) {
  int idx = blockIdx.x * 256 + threadIdx.x;
  int k = idx & ((1 << kshift) - 1);
  int n = idx >> kshift;
  float f = W[(size_t)k * Nc + n];
  unsigned u = __float_as_uint(f);
  WThi[idx] = (ushort_t)(u >> 16);
  float lo = f - __uint_as_float(u & 0xFFFF0000u);
  WTlo[idx] = (ushort_t)(__float_as_uint(lo) >> 16);
}

// ---------------------------------------------------------------------------
// Producer GEMM, full split precision (3 MFMA): C = A(fp32)[M,K] @ B, with
// B transposed split BT[NC][K]. REGISTER-DIRECT (no LDS/barriers in K-loop;
// r7 showed this structure moves the counters). Block tile 128 x NCB,
// 2x2 waves of 64m x NCB/2 each — doubled M-tile vs r7 so per-wave B-ingest
// (8KB/step) feeds 2x the MFMAs and A-read/split-VALU dup halves per row.
// gridDim.y = NC/NCB. Outputs: CT split, tile-blocked CT_t[tile=M/64][NC][64]
// (each block writes two 64-row tiles); el/er partial row dots atomicAdd'ed.
// ---------------------------------------------------------------------------
template<int NC, int NCB>
__global__ __launch_bounds__(256, 2) void gemm_asplit(const float* __restrict__ A,
                                                      const ushort_t* __restrict__ BThi,
                                                      const ushort_t* __restrict__ BTlo,
                                                      const float* __restrict__ avec,
                                                      ushort_t* __restrict__ CThi,
                                                      ushort_t* __restrict__ CTlo,
                                                      float* __restrict__ el,
                                                      float* __restrict__ er, int K) {
  constexpr int NFR = NCB / 32;        // n-frags per wave (wave tile 64 x NCB/2)
  __shared__ ushort_t stg[NCB * 130];  // CT epilogue staging only
  const int t = threadIdx.x, lane = t & 63, wid = t >> 6;
  const int wm = (wid & 1) * 64, wn = (wid >> 1) * (NCB / 2);
  const int ln = lane & 15, quad = lane >> 4;
  const int m0 = blockIdx.x * 128;
  const int n0c = blockIdx.y * NCB;
  const float*    ap  = A    + (size_t)(m0 + wm + ln) * K + quad * 8;
  const ushort_t* bh0 = BThi + (size_t)(n0c + wn + ln) * K + quad * 8;
  const ushort_t* bl0 = BTlo + (size_t)(n0c + wn + ln) * K + quad * 8;
  f32x4 acc[4][NFR];
#pragma unroll
  for (int mi = 0; mi < 4; ++mi)
#pragma unroll
    for (int ni = 0; ni < NFR; ++ni) acc[mi][ni] = (f32x4){0.f, 0.f, 0.f, 0.f};

  for (int k0 = 0; k0 < K; k0 += 32) {
    bf16x8 ahf[4], alf[4];
#pragma unroll
    for (int mi = 0; mi < 4; ++mi) {
      const float* app = ap + (size_t)(mi * 16) * K + k0;
      float4 f0 = *(const float4*)(app);
      float4 f1 = *(const float4*)(app + 4);
      uint4 hv, lv;
      split_pack2(f0.x, f0.y, hv.x, lv.x);
      split_pack2(f0.z, f0.w, hv.y, lv.y);
      split_pack2(f1.x, f1.y, hv.z, lv.z);
      split_pack2(f1.z, f1.w, hv.w, lv.w);
      ahf[mi] = *(bf16x8*)&hv; alf[mi] = *(bf16x8*)&lv;
    }
    bf16x8 bhf[NFR], blf[NFR];
#pragma unroll
    for (int i = 0; i < NFR; ++i) {
      uint4 vh = *(const uint4*)(bh0 + (size_t)i * 16 * K + k0);
      uint4 vl = *(const uint4*)(bl0 + (size_t)i * 16 * K + k0);
      bhf[i] = *(bf16x8*)&vh; blf[i] = *(bf16x8*)&vl;
    }
#pragma unroll
    for (int mi = 0; mi < 4; ++mi)
#pragma unroll
      for (int ni = 0; ni < NFR; ++ni) {
        acc[mi][ni] = __builtin_amdgcn_mfma_f32_16x16x32_bf16(ahf[mi], bhf[ni], acc[mi][ni], 0, 0, 0);
        acc[mi][ni] = __builtin_amdgcn_mfma_f32_16x16x32_bf16(ahf[mi], blf[ni], acc[mi][ni], 0, 0, 0);
        acc[mi][ni] = __builtin_amdgcn_mfma_f32_16x16x32_bf16(alf[mi], bhf[ni], acc[mi][ni], 0, 0, 0);
      }
  }

  // ---- el/er partial row-dot reduction over this block's NCB cols ----
  float aLc[NFR], aRc[NFR];
#pragma unroll
  for (int ni = 0; ni < NFR; ++ni) {
    aLc[ni] = avec[n0c + wn + ni * 16 + ln];
    aRc[ni] = avec[NC + n0c + wn + ni * 16 + ln];
  }
#pragma unroll
  for (int mi = 0; mi < 4; ++mi) {
    const int mr = m0 + wm + mi * 16 + quad * 4;
#pragma unroll
    for (int rr = 0; rr < 4; ++rr) {
      float vel = 0.f, ver = 0.f;
#pragma unroll
      for (int ni = 0; ni < NFR; ++ni) {
        vel = fmaf(acc[mi][ni][rr], aLc[ni], vel);
        ver = fmaf(acc[mi][ni][rr], aRc[ni], ver);
      }
#pragma unroll
      for (int m = 1; m < 16; m <<= 1) {
        vel += __shfl_xor(vel, m);
        ver += __shfl_xor(ver, m);
      }
      if (ln == 0) {
        atomicAdd(&el[mr + rr], vel);
        atomicAdd(&er[mr + rr], ver);
      }
    }
  }

  // ---- staged CT write: block's 128 rows -> two 64-row tiles, contiguous ----
  // stg layout: [NCB cols][130 rows-padded] ushort.
  ushort_t* dsthi = CThi + (size_t)(2 * blockIdx.x) * (NC * 64) + (size_t)n0c * 64;
  ushort_t* dstlo = CTlo + (size_t)(2 * blockIdx.x) * (NC * 64) + (size_t)n0c * 64;
#pragma unroll
  for (int pass = 0; pass < 2; ++pass) {
    if (pass) __syncthreads();   // protect pass-0 reads from pass-1 writes
#pragma unroll
    for (int mi = 0; mi < 4; ++mi) {
      const int rbase = wm + mi * 16 + quad * 4;
#pragma unroll
      for (int ni = 0; ni < NFR; ++ni) {
        const int c = wn + ni * 16 + ln;
        unsigned h01, l01, h23, l23;
        split_pack2(acc[mi][ni][0], acc[mi][ni][1], h01, l01);
        split_pack2(acc[mi][ni][2], acc[mi][ni][3], h23, l23);
        uint2 v = pass ? make_uint2(l01, l23) : make_uint2(h01, h23);
        *(uint2*)&stg[c * 130 + rbase] = v;
      }
    }
    __syncthreads();
    ushort_t* dst = pass ? dstlo : dsthi;
    const int r = (t & 15) * 8;          // 0..120, 8-row (16B) chunks
    const size_t half = (size_t)(r >> 6) * (NC * 64) + (r & 63);
#pragma unroll
    for (int cc = 0; cc < NCB / 16; ++cc) {
      const int col = cc * 16 + (t >> 4);
      *(uint4*)&dst[half + (size_t)col * 64] = *(const uint4*)&stg[col * 130 + r];
    }
  }
}

// Per-batch min/max of el, er -> (mn, 30/(mx-mn)); leaky is monotone.
__global__ __launch_bounds__(256) void minmax_params(const float* __restrict__ el,
                                                     const float* __restrict__ er,
                                                     float2* __restrict__ params) {
  __shared__ float smnl[256], smxl[256], smnr[256], smxr[256];
  const int b = blockIdx.x, t = threadIdx.x;
  float mnl = 3.4e38f, mxl = -3.4e38f, mnr = 3.4e38f, mxr = -3.4e38f;
  for (int i = t; i < NN; i += 256) {
    float v = el[b * NN + i];
    mnl = fminf(mnl, v); mxl = fmaxf(mxl, v);
    float u = er[b * NN + i];
    mnr = fminf(mnr, u); mxr = fmaxf(mxr, u);
  }
  smnl[t] = mnl; smxl[t] = mxl; smnr[t] = mnr; smxr[t] = mxr;
  __syncthreads();
  for (int s = 128; s > 0; s >>= 1) {
    if (t < s) {
      smnl[t] = fminf(smnl[t], smnl[t + s]);
      smxl[t] = fmaxf(smxl[t], smxl[t + s]);
      smnr[t] = fminf(smnr[t], smnr[t + s]);
      smxr[t] = fmaxf(smxr[t], smxr[t + s]);
    }
    __syncthreads();
  }
  if (t == 0) {
    float mn = leakyf(smnl[0] + smnr[0]);
    float mx = leakyf(smxl[0] + smxr[0]);
    params[b] = make_float2(mn, 30.0f / (mx - mn));
  }
}

// ---------------------------------------------------------------------------
// Attention MFMA GEMM: C[i,f] = sum_j att(i,j)*h[j,f]. att synthesized fp32,
// RNE bf16 hi-only A-operand; h split B-operand (2 MFMA). REGISTER-DIRECT
// (r7 structure) with DOUBLED tile: 128 x BW, 2x2 waves of 64m x BW/2 —
// same per-wave B-ingest now feeds 2x MFMAs; sigmoid cost per output row
// halves. Each lane computes its att fragment (32 sigmoids/step) and loads
// its h fragment straight from global (tile-blocked CT_t[tile][Nc][64]).
// Only LDS: read-only ers[] broadcast table (one barrier at start).
// doElu: stage-1 epilogue. wg!=null: fuse wv[row] += sum_{f in block} C*wg[f].
// ---------------------------------------------------------------------------
template<int BW>
__global__ __launch_bounds__(256, 2) void gemm_att2(const float* __restrict__ el,
                                                    const float* __restrict__ er,
                                                    const float2* __restrict__ params,
                                                    const ushort_t* __restrict__ hThi,
                                                    const ushort_t* __restrict__ hTlo,
                                                    float* __restrict__ C,
                                                    const float* __restrict__ wg,
                                                    float* __restrict__ wv,
                                                    int Nc, int doElu) {
  constexpr int NFR = BW / 32;
  __shared__ float ers[NN];
  const int b = blockIdx.z, t = threadIdx.x, lane = t & 63, wid = t >> 6;
  const int wm = (wid & 1) * 64, wn = (wid >> 1) * (BW / 2);
  const int ln = lane & 15, quad = lane >> 4;
  const int m0 = blockIdx.x * 128, n0 = blockIdx.y * BW;
  const float2 p = params[b];
  const float npinv = -p.y;                  // q = exp(-e_s)
  const float npc   = p.x * p.y + 20.0f;
  *(float4*)&ers[t * 4] = *(const float4*)&er[b * NN + t * 4];
  float elvv[4];
#pragma unroll
  for (int mi = 0; mi < 4; ++mi) elvv[mi] = el[b * NN + m0 + wm + mi * 16 + ln];
  const size_t tstride = (size_t)Nc * 64;                 // ushorts per tile
  const ushort_t* bh0 = hThi + (size_t)(b * 16) * tstride + (size_t)(n0 + wn + ln) * 64 + quad * 8;
  const ushort_t* bl0 = hTlo + (size_t)(b * 16) * tstride + (size_t)(n0 + wn + ln) * 64 + quad * 8;
  f32x4 acc[4][NFR];
#pragma unroll
  for (int mi = 0; mi < 4; ++mi)
#pragma unroll
    for (int ni = 0; ni < NFR; ++ni) acc[mi][ni] = (f32x4){0.f, 0.f, 0.f, 0.f};
  __syncthreads();   // ers visible

  for (int k0 = 0; k0 < NN; k0 += 32) {
    float e8[8];
    *(float4*)&e8[0] = *(const float4*)&ers[k0 + quad * 8];
    *(float4*)&e8[4] = *(const float4*)&ers[k0 + quad * 8 + 4];
    bf16x8 af[4];
#pragma unroll
    for (int mi = 0; mi < 4; ++mi) {
      const float elv = elvv[mi];
      float s[8];
#pragma unroll
      for (int j = 0; j < 8; ++j) {
        float x = elv + e8[j];
        x = fmaxf(x, 0.01f * x);
        s[j] = __builtin_amdgcn_rcpf(1.0f + __expf(fmaf(x, npinv, npc)));
      }
      uint4 av;
      av.x = pack_rne(s[0], s[1]); av.y = pack_rne(s[2], s[3]);
      av.z = pack_rne(s[4], s[5]); av.w = pack_rne(s[6], s[7]);
      af[mi] = *(bf16x8*)&av;
    }
    const size_t ko = (size_t)(k0 >> 6) * tstride + (size_t)(k0 & 32);
    bf16x8 bhf[NFR], blf[NFR];
#pragma unroll
    for (int i = 0; i < NFR; ++i) {
      uint4 vh = *(const uint4*)(bh0 + ko + i * (16 * 64));
      uint4 vl = *(const uint4*)(bl0 + ko + i * (16 * 64));
      bhf[i] = *(bf16x8*)&vh; blf[i] = *(bf16x8*)&vl;
    }
#pragma unroll
    for (int mi = 0; mi < 4; ++mi)
#pragma unroll
      for (int ni = 0; ni < NFR; ++ni) {
        acc[mi][ni] = __builtin_amdgcn_mfma_f32_16x16x32_bf16(af[mi], bhf[ni], acc[mi][ni], 0, 0, 0);
        acc[mi][ni] = __builtin_amdgcn_mfma_f32_16x16x32_bf16(af[mi], blf[ni], acc[mi][ni], 0, 0, 0);
      }
  }
  float wgl[NFR];
  if (wg) {
#pragma unroll
    for (int ni = 0; ni < NFR; ++ni) wgl[ni] = wg[n0 + wn + ni * 16 + ln];
  }
#pragma unroll
  for (int mi = 0; mi < 4; ++mi) {
    const int mrl = m0 + wm + mi * 16 + quad * 4;         // row within batch
    const size_t mrow = (size_t)b * NN + mrl;
#pragma unroll
    for (int ni = 0; ni < NFR; ++ni) {
      const int c = n0 + wn + ni * 16 + ln;
#pragma unroll
      for (int rr = 0; rr < 4; ++rr) {
        float v = acc[mi][ni][rr];
        if (doElu) v = eluf(v);
        C[(mrow + rr) * Nc + c] = v;
      }
    }
    if (wg) {
#pragma unroll
      for (int rr = 0; rr < 4; ++rr) {
        float vw = 0.f;
#pragma unroll
        for (int ni = 0; ni < NFR; ++ni)
          vw = fmaf(acc[mi][ni][rr], wgl[ni], vw);
#pragma unroll
        for (int m = 1; m < 16; m <<= 1) vw += __shfl_xor(vw, m);
        if (ln == 0) atomicAdd(&wv[b * NN + mrl + rr], vw);
      }
    }
  }
}

// ---------------------------------------------------------------------------
// Fused: fc2[b,i,j] = att2(i,j) (fp32) AND out[b,i] = leaky(sum_j att*w + bg).
// One wave per row i; lanes cover 4 consecutive j each (coalesced float4).
// ---------------------------------------------------------------------------
__global__ __launch_bounds__(256) void final_out_fc2(const float* __restrict__ el,
                                                     const float* __restrict__ er,
                                                     const float2* __restrict__ params,
                                                     const float* __restrict__ w,
                                                     const float* __restrict__ bg,
                                                     float* __restrict__ fc2,
                                                     float* __restrict__ out) {
  const int row  = (blockIdx.x * 256 + threadIdx.x) >> 6;  // b*N+i
  const int lane = threadIdx.x & 63;
  const int b = row >> 10;
  const float2 p = params[b];
  const float npinv = -p.y;
  const float npc   = p.x * p.y + 20.0f;
  const float eli = el[row];
  const float* erb = er + (b << 10);
  const float* wb  = w + (b << 10);
  float* fcrow = fc2 + (size_t)row * NN;
  float s = 0.f;
  for (int j = lane * 4; j < NN; j += 256) {
    float4 e4 = *(const float4*)&erb[j];
    float4 w4 = *(const float4*)&wb[j];
    float4 a;
    a.x = __builtin_amdgcn_rcpf(1.0f + __expf(fmaf(leakyf(eli + e4.x), npinv, npc)));
    a.y = __builtin_amdgcn_rcpf(1.0f + __expf(fmaf(leakyf(eli + e4.y), npinv, npc)));
    a.z = __builtin_amdgcn_rcpf(1.0f + __expf(fmaf(leakyf(eli + e4.z), npinv, npc)));
    a.w = __builtin_amdgcn_rcpf(1.0f + __expf(fmaf(leakyf(eli + e4.w), npinv, npc)));
    s += w4.x * a.x + w4.y * a.y + w4.z * a.z + w4.w * a.w;
    *(float4*)&fcrow[j] = a;
  }
#pragma unroll
  for (int off = 32; off > 0; off >>= 1) s += __shfl_down(s, off);
  if (lane == 0) out[row] = leakyf(s + bg[0]);
}

extern "C" void kernel_launch(void* const* d_in, const int* in_sizes, int n_in,
                              void* d_out, int out_size, void* d_ws, size_t ws_size,
                              hipStream_t stream) {
  (void)in_sizes; (void)n_in; (void)out_size; (void)ws_size;
  const float* x  = (const float*)d_in[0];
  const float* W1 = (const float*)d_in[2];
  const float* a1 = (const float*)d_in[3];
  const float* W2 = (const float*)d_in[4];
  const float* a2 = (const float*)d_in[5];
  const float* Wg = (const float*)d_in[6];
  const float* bg = (const float*)d_in[7];

  float* out = (float*)d_out;               // [B,N,1]   32768
  float* fc2 = out + 32768;                 // [B,N,N]   33554432
  float* g2  = fc2 + 33554432;              // [B,N,H2]  4194304

  // Scratch inside the fc2 region (fc2 is written LAST, by final_out_fc2).
  ushort_t* h1Thi = (ushort_t*)fc2;                     // [512][256][64] tiled
  ushort_t* h1Tlo = (ushort_t*)(fc2 + 4194304);
  float*    g1    = fc2 + 8388608;                      // [32768][256] fp32
  ushort_t* h2Thi = (ushort_t*)(fc2 + 16777216);        // [512][128][64] tiled
  ushort_t* h2Tlo = (ushort_t*)(fc2 + 18874368);

  float* wsf = (float*)d_ws;
  float* el1 = wsf;                          // 32768 each; el1,er1,el2,er2,wv
  float* er1 = wsf + 32768;                  //   contiguous -> single memset
  float* el2 = wsf + 65536;
  float* er2 = wsf + 98304;
  float* wv  = wsf + 131072;
  float2* p1 = (float2*)(wsf + 163840);      // 32 float2
  float2* p2 = (float2*)(wsf + 163904);
  ushort_t* W1Thi = (ushort_t*)(wsf + 163968);   // [256][512]
  ushort_t* W1Tlo = (ushort_t*)(wsf + 229504);
  ushort_t* W2Thi = (ushort_t*)(wsf + 295040);   // [128][256]
  ushort_t* W2Tlo = (ushort_t*)(wsf + 311424);

  dim3 blk(256);
  hipMemsetAsync(wsf, 0, 5u * 32768u * sizeof(float), stream);   // el/er/wv = 0
  transpose_w_split<<<512, blk, 0, stream>>>(W1, W1Thi, W1Tlo, HH1, 9);
  transpose_w_split<<<128, blk, 0, stream>>>(W2, W2Thi, W2Tlo, HH2, 8);
  // Stage 1
  gemm_asplit<HH1, 128><<<dim3(256, 2), blk, 0, stream>>>(x, W1Thi, W1Tlo, a1,
                                                          h1Thi, h1Tlo, el1, er1, FIN);
  minmax_params<<<32, blk, 0, stream>>>(el1, er1, p1);
  gemm_att2<128><<<dim3(8, 2, 32), blk, 0, stream>>>(el1, er1, p1, h1Thi, h1Tlo,
                                                     g1, nullptr, nullptr, HH1, 1);
  // Stage 2
  gemm_asplit<HH2, 64><<<dim3(256, 2), blk, 0, stream>>>(g1, W2Thi, W2Tlo, a2,
                                                         h2Thi, h2Tlo, el2, er2, HH1);
  minmax_params<<<32, blk, 0, stream>>>(el2, er2, p2);
  gemm_att2<64><<<dim3(8, 2, 32), blk, 0, stream>>>(el2, er2, p2, h2Thi, h2Tlo,
                                                    g2, Wg, wv, HH2, 0);
  // Stage 3: fc2 + out (att recomputed on the fly; wv = g2 @ Wg already fused)
  final_out_fc2<<<8192, blk, 0, stream>>>(el2, er2, p2, wv, bg, fc2, out);
}